// Round 2
// baseline (12503.353 us; speedup 1.0000x reference)
//
#include <hip/hip_runtime.h>
#include <math.h>

#define B_ 64
#define T_ 2048
#define D_ 512
#define BT_ (B_ * T_)   // 131072
#define NGRP 4          // blocks per batch (channel quarters)
#define FSTRIDE 16      // flag padding (ints)
#define XCHG_HALF (NGRP * 64 * 128)   // 32768 floats per parity slot

typedef float f32x4 __attribute__((ext_vector_type(4)));

// ---------------------------------------------------------------------------
// Kernel 1: weight prep (transpose to k-major for coalesced GEMM/GEMV reads)
//   Wcat[k][j], j<512:  tau_w[j*1024 + k]      (x -> gate half)
//              j>=512:  mem_w[(j-512)*512 + k] (x -> mem)
//   WTh[k][d]        :  tau_w[d*1024 + 512+k]  (tau -> gate recurrent half)
// ---------------------------------------------------------------------------
__global__ void prep_weights(const float* __restrict__ tau_w,
                             const float* __restrict__ mem_w,
                             float* __restrict__ Wcat,
                             float* __restrict__ WTh) {
    int idx = blockIdx.x * 256 + threadIdx.x;   // 0 .. 524287
    {
        int k = idx >> 10, j = idx & 1023;
        float v = (j < 512) ? tau_w[j * 1024 + k] : mem_w[(j - 512) * 512 + k];
        Wcat[idx] = v;
    }
    if (idx < 512 * 512) {
        int k = idx >> 9, d = idx & 511;
        WTh[idx] = tau_w[d * 1024 + 512 + k];
    }
}

// ---------------------------------------------------------------------------
// Kernel 2: f32 GEMM  C[131072][1024] = X[131072][512] @ Wcat[512][1024] + bias
//   cols 0..511   -> Aout (spikes region of d_out, overwritten later by scan)
//   cols 512..1023-> Mout (workspace)
// ---------------------------------------------------------------------------
__global__ __launch_bounds__(256, 2)
void gemm_xw(const float* __restrict__ X, const float* __restrict__ Wc,
             const float* __restrict__ tau_b, const float* __restrict__ mem_b,
             float* __restrict__ Aout, float* __restrict__ Mout) {
    __shared__ __align__(16) float As[16][128];  // [k][m]
    __shared__ __align__(16) float Bs[16][128];  // [k][n]
    const int bn = blockIdx.x;          // 0..7
    const int bm = blockIdx.y;          // 0..1023
    const int tid = threadIdx.x;
    const int tm = (tid >> 4) << 3;
    const int tn = (tid & 15) << 3;
    const int m0 = bm * 128, n0 = bn * 128;

    const float4* X4 = (const float4*)X;
    const float4* Wc4 = (const float4*)Wc;

    float acc[8][8];
#pragma unroll
    for (int i = 0; i < 8; i++)
#pragma unroll
        for (int j = 0; j < 8; j++) acc[i][j] = 0.0f;

    const int ar = tid >> 1;              // 0..127 row in tile
    const int ac2 = (tid & 1) * 2;        // float4 col 0 or 2
    const int bkr = tid >> 4;             // 0..15
    const int bc = (tid & 15) * 2;        // float4 col 0..30

    for (int kt = 0; kt < 512; kt += 16) {
        float4 av0 = X4[(m0 + ar) * 128 + (kt >> 2) + ac2];
        float4 av1 = X4[(m0 + ar) * 128 + (kt >> 2) + ac2 + 1];
        float4 bv0 = Wc4[(kt + bkr) * 256 + bn * 32 + bc];
        float4 bv1 = Wc4[(kt + bkr) * 256 + bn * 32 + bc + 1];
        __syncthreads();   // protect previous iteration's reads
        As[ac2 * 4 + 0][ar] = av0.x;
        As[ac2 * 4 + 1][ar] = av0.y;
        As[ac2 * 4 + 2][ar] = av0.z;
        As[ac2 * 4 + 3][ar] = av0.w;
        As[ac2 * 4 + 4][ar] = av1.x;
        As[ac2 * 4 + 5][ar] = av1.y;
        As[ac2 * 4 + 6][ar] = av1.z;
        As[ac2 * 4 + 7][ar] = av1.w;
        *(float4*)&Bs[bkr][bc * 4] = bv0;
        *(float4*)&Bs[bkr][bc * 4 + 4] = bv1;
        __syncthreads();
#pragma unroll
        for (int kk = 0; kk < 16; kk++) {
            float4 a0 = *(const float4*)&As[kk][tm];
            float4 a1 = *(const float4*)&As[kk][tm + 4];
            float4 b0 = *(const float4*)&Bs[kk][tn];
            float4 b1 = *(const float4*)&Bs[kk][tn + 4];
            float av[8] = {a0.x, a0.y, a0.z, a0.w, a1.x, a1.y, a1.z, a1.w};
            float bv[8] = {b0.x, b0.y, b0.z, b0.w, b1.x, b1.y, b1.z, b1.w};
#pragma unroll
            for (int i = 0; i < 8; i++)
#pragma unroll
                for (int j = 0; j < 8; j++)
                    acc[i][j] = fmaf(av[i], bv[j], acc[i][j]);
        }
    }

    const bool isA = (bn < 4);
    float* Cout = isA ? Aout : Mout;
    const float* bias = isA ? tau_b : mem_b;
    const int ncol0 = (isA ? n0 : n0 - 512) + tn;
    float bj[8];
#pragma unroll
    for (int j = 0; j < 8; j++) bj[j] = bias[ncol0 + j];
#pragma unroll
    for (int i = 0; i < 8; i++) {
        size_t off = (size_t)(m0 + tm + i) * 512 + ncol0;
        float4 o0, o1;
        o0.x = acc[i][0] + bj[0]; o0.y = acc[i][1] + bj[1];
        o0.z = acc[i][2] + bj[2]; o0.w = acc[i][3] + bj[3];
        o1.x = acc[i][4] + bj[4]; o1.y = acc[i][5] + bj[5];
        o1.z = acc[i][6] + bj[6]; o1.w = acc[i][7] + bj[7];
        *(float4*)&Cout[off] = o0;
        *(float4*)&Cout[off + 4] = o1;
    }
}

// ---------------------------------------------------------------------------
// Kernel 3: reset sync state (runs every launch -> graph-replay safe).
// Slot-0 of xchg holds s_0 = initial tau = ones; flags = 0.
// ---------------------------------------------------------------------------
__global__ void init_sync(float* __restrict__ xchg, int* __restrict__ flags) {
    int idx = blockIdx.x * 256 + threadIdx.x;
    if (idx < XCHG_HALF) xchg[idx] = 1.0f;
    if (idx < 256 * FSTRIDE) flags[idx] = 0;
}

// ---------------------------------------------------------------------------
// Kernel 4: cooperative scan. 256 blocks = (batch bb, channel-quarter cq).
// Each block owns 128 output channels; its 512x128 weight slice lives
// entirely in VGPRs (2 channels x 64 k per thread = 32 float4).
// Per step: gather full tau (4 segments via agent-scope loads), GEMV,
// epilogue on 128 threads, publish segment + flag.
// ---------------------------------------------------------------------------
__global__ __launch_bounds__(512, 2)
void scan_sync(const float* __restrict__ WTh,
               const float* __restrict__ Mm,
               const float* __restrict__ log_thresh,
               float* __restrict__ AmOut,   // A in / spikes out (d_out)
               float* __restrict__ OutTail, // d_out base for tau/v tails
               float* __restrict__ xchg,
               int* __restrict__ flags) {
    __shared__ __align__(16) float tau_s[512];
    __shared__ __align__(16) float part[8][128];

    const int blk = blockIdx.x;
    const int bb = blk & 63;     // batch
    const int cq = blk >> 6;     // channel quarter 0..3
    const int tid = threadIdx.x;

    const int kg = tid >> 6;     // k-eighth 0..7 (wave-uniform)
    const int dd6 = tid & 63;
    const int k0 = kg << 6;

    const int gj = tid >> 7;     // tau segment this thread gathers/waits on
    const int gd = tid & 127;

    const int de = cq * 128 + (tid & 127);   // epilogue channel (tid<128)

    // weight fragment: channels c0 = cq*128+dd6, c1 = c0+64; k in [k0,k0+64)
    f32x4 w0[16], w1[16];
    {
        const int c0 = cq * 128 + dd6;
        const int c1 = c0 + 64;
#pragma unroll
        for (int j = 0; j < 16; j++) {
            int k = k0 + 4 * j;
            w0[j].x = WTh[(k + 0) * 512 + c0];
            w0[j].y = WTh[(k + 1) * 512 + c0];
            w0[j].z = WTh[(k + 2) * 512 + c0];
            w0[j].w = WTh[(k + 3) * 512 + c0];
            w1[j].x = WTh[(k + 0) * 512 + c1];
            w1[j].y = WTh[(k + 1) * 512 + c1];
            w1[j].z = WTh[(k + 2) * 512 + c1];
            w1[j].w = WTh[(k + 3) * 512 + c1];
        }
    }

    float thr = 0.f, v = 0.f, tau_new = 0.f;
    if (tid < 128) thr = 1.0f / (1.0f + expf(-log_thresh[de]));

    const f32x4* tau4 = (const f32x4*)tau_s;
    size_t abase = (size_t)bb * T_ * D_ + de;
    int* myflag = &flags[(bb * NGRP + cq) * FSTRIDE];
    const int* gflag = &flags[(bb * NGRP + gj) * FSTRIDE];
    const bool selfseg = (gj == cq);

    for (int c = 1; c <= T_; c++) {
        // early-issue this step's A and M (consumed after GEMV)
        float a_in = 0.f, m_in = 0.f;
        if (tid < 128) { a_in = AmOut[abase]; m_in = Mm[abase]; }

        // wait for segment gj to have published s_{c-1}
        if (!selfseg) {
            while (__hip_atomic_load(gflag, __ATOMIC_RELAXED,
                                     __HIP_MEMORY_SCOPE_AGENT) < c - 1) {}
        }
        asm volatile("" ::: "memory");   // no load motion above the spin
        tau_s[tid] = __hip_atomic_load(
            &xchg[(size_t)((c - 1) & 1) * XCHG_HALF + gj * 8192 + bb * 128 + gd],
            __ATOMIC_RELAXED, __HIP_MEMORY_SCOPE_AGENT);
        __syncthreads();

        // keep the weight fragment pinned in VGPRs each iteration
        asm volatile("" :: "v"(w0[0]), "v"(w0[1]), "v"(w0[2]), "v"(w0[3]),
                           "v"(w0[4]), "v"(w0[5]), "v"(w0[6]), "v"(w0[7]));
        asm volatile("" :: "v"(w0[8]), "v"(w0[9]), "v"(w0[10]), "v"(w0[11]),
                           "v"(w0[12]), "v"(w0[13]), "v"(w0[14]), "v"(w0[15]));
        asm volatile("" :: "v"(w1[0]), "v"(w1[1]), "v"(w1[2]), "v"(w1[3]),
                           "v"(w1[4]), "v"(w1[5]), "v"(w1[6]), "v"(w1[7]));
        asm volatile("" :: "v"(w1[8]), "v"(w1[9]), "v"(w1[10]), "v"(w1[11]),
                           "v"(w1[12]), "v"(w1[13]), "v"(w1[14]), "v"(w1[15]));

        float acc0 = 0.f, acc1 = 0.f;
#pragma unroll
        for (int j = 0; j < 16; j++) {
            f32x4 tv = tau4[kg * 16 + j];     // wave-uniform LDS broadcast
            acc0 = fmaf(tv.x, w0[j].x, acc0);
            acc0 = fmaf(tv.y, w0[j].y, acc0);
            acc0 = fmaf(tv.z, w0[j].z, acc0);
            acc0 = fmaf(tv.w, w0[j].w, acc0);
            acc1 = fmaf(tv.x, w1[j].x, acc1);
            acc1 = fmaf(tv.y, w1[j].y, acc1);
            acc1 = fmaf(tv.z, w1[j].z, acc1);
            acc1 = fmaf(tv.w, w1[j].w, acc1);
        }
        part[kg][dd6] = acc0;
        part[kg][64 + dd6] = acc1;
        __syncthreads();

        if (tid < 128) {
            const int dch = tid;
            float p = ((part[0][dch] + part[1][dch]) + (part[2][dch] + part[3][dch]))
                    + ((part[4][dch] + part[5][dch]) + (part[6][dch] + part[7][dch]));
            float pre = p + a_in;
            tau_new = 1.0f / (1.0f + expf(-pre));
            float alpha = expf(-1.0f / (tau_new + 1e-6f));
            v = alpha * v + (1.0f - alpha) * m_in;
            float s = (v >= thr) ? 1.0f : 0.0f;
            AmOut[abase] = s;           // overwrite A slot with spike
            v = v * (1.0f - s);
            __hip_atomic_store(
                &xchg[(size_t)(c & 1) * XCHG_HALF + cq * 8192 + bb * 128 + tid],
                tau_new, __ATOMIC_RELAXED, __HIP_MEMORY_SCOPE_AGENT);
            abase += D_;
        }
        __syncthreads();   // publish stores drained (vmcnt) before flag
        if (tid == 0)
            __hip_atomic_store(myflag, c, __ATOMIC_RELEASE,
                               __HIP_MEMORY_SCOPE_AGENT);
    }

    if (tid < 128) {
        OutTail[(size_t)BT_ * D_ + (size_t)bb * D_ + de] = tau_new;
        OutTail[(size_t)BT_ * D_ + (size_t)B_ * D_ + (size_t)bb * D_ + de] = v;
    }
}

// ---------------------------------------------------------------------------
extern "C" void kernel_launch(void* const* d_in, const int* in_sizes, int n_in,
                              void* d_out, int out_size, void* d_ws, size_t ws_size,
                              hipStream_t stream) {
    (void)in_sizes; (void)n_in; (void)out_size; (void)ws_size;
    const float* x          = (const float*)d_in[0];
    const float* tau_w      = (const float*)d_in[1];
    const float* tau_b      = (const float*)d_in[2];
    const float* mem_w      = (const float*)d_in[3];
    const float* mem_b      = (const float*)d_in[4];
    const float* log_thresh = (const float*)d_in[5];
    float* out = (float*)d_out;

    // workspace layout
    float* Wcat = (float*)d_ws;            // 512*1024 (dead after GEMM)
    float* WTh  = Wcat + 512 * 1024;       // 512*512
    float* Mout = WTh + 512 * 512;         // 131072*512
    // sync state reuses the Wcat region (GEMM is done before init_sync runs)
    float* xchg  = Wcat;                              // 2*XCHG_HALF floats
    int*   flags = (int*)(Wcat + 2 * XCHG_HALF);      // 256*FSTRIDE ints

    float* Aout = out;                     // spikes region doubles as A buffer

    prep_weights<<<2048, 256, 0, stream>>>(tau_w, mem_w, Wcat, WTh);
    gemm_xw<<<dim3(8, 1024), 256, 0, stream>>>(x, Wcat, tau_b, mem_b, Aout, Mout);
    init_sync<<<128, 256, 0, stream>>>(xchg, flags);

    const float* WThc = WTh;
    const float* Mmc  = Mout;
    const float* ltc  = log_thresh;
    float* outp = out;
    float* xchgp = xchg;
    int* flagsp = flags;
    void* args[7] = {(void*)&WThc, (void*)&Mmc, (void*)&ltc,
                     (void*)&Aout, (void*)&outp, (void*)&xchgp, (void*)&flagsp};
    hipLaunchCooperativeKernel((const void*)scan_sync, dim3(256), dim3(512),
                               args, 0, stream);
}

// Round 3
// 11729.586 us; speedup vs baseline: 1.0660x; 1.0660x over previous
//
#include <hip/hip_runtime.h>
#include <math.h>

#define B_ 64
#define T_ 2048
#define D_ 512
#define BT_ (B_ * T_)   // 131072
#define NGRP 4          // blocks per batch (channel quarters)
#define FSTRIDE 16      // flag padding (ints)
#define XCHG_HALF (NGRP * 64 * 128)   // 32768 floats per parity slot

typedef float f32x4 __attribute__((ext_vector_type(4)));

// ---------------------------------------------------------------------------
// Kernel 1: weight prep (transpose to k-major for coalesced GEMM/GEMV reads)
// ---------------------------------------------------------------------------
__global__ void prep_weights(const float* __restrict__ tau_w,
                             const float* __restrict__ mem_w,
                             float* __restrict__ Wcat,
                             float* __restrict__ WTh) {
    int idx = blockIdx.x * 256 + threadIdx.x;   // 0 .. 524287
    {
        int k = idx >> 10, j = idx & 1023;
        float v = (j < 512) ? tau_w[j * 1024 + k] : mem_w[(j - 512) * 512 + k];
        Wcat[idx] = v;
    }
    if (idx < 512 * 512) {
        int k = idx >> 9, d = idx & 511;
        WTh[idx] = tau_w[d * 1024 + 512 + k];
    }
}

// ---------------------------------------------------------------------------
// Kernel 2: f32 GEMM  C[131072][1024] = X[131072][512] @ Wcat[512][1024] + bias
// ---------------------------------------------------------------------------
__global__ __launch_bounds__(256, 2)
void gemm_xw(const float* __restrict__ X, const float* __restrict__ Wc,
             const float* __restrict__ tau_b, const float* __restrict__ mem_b,
             float* __restrict__ Aout, float* __restrict__ Mout) {
    __shared__ __align__(16) float As[16][128];  // [k][m]
    __shared__ __align__(16) float Bs[16][128];  // [k][n]
    const int bn = blockIdx.x;          // 0..7
    const int bm = blockIdx.y;          // 0..1023
    const int tid = threadIdx.x;
    const int tm = (tid >> 4) << 3;
    const int tn = (tid & 15) << 3;
    const int m0 = bm * 128, n0 = bn * 128;

    const float4* X4 = (const float4*)X;
    const float4* Wc4 = (const float4*)Wc;

    float acc[8][8];
#pragma unroll
    for (int i = 0; i < 8; i++)
#pragma unroll
        for (int j = 0; j < 8; j++) acc[i][j] = 0.0f;

    const int ar = tid >> 1;              // 0..127 row in tile
    const int ac2 = (tid & 1) * 2;        // float4 col 0 or 2
    const int bkr = tid >> 4;             // 0..15
    const int bc = (tid & 15) * 2;        // float4 col 0..30

    for (int kt = 0; kt < 512; kt += 16) {
        float4 av0 = X4[(m0 + ar) * 128 + (kt >> 2) + ac2];
        float4 av1 = X4[(m0 + ar) * 128 + (kt >> 2) + ac2 + 1];
        float4 bv0 = Wc4[(kt + bkr) * 256 + bn * 32 + bc];
        float4 bv1 = Wc4[(kt + bkr) * 256 + bn * 32 + bc + 1];
        __syncthreads();   // protect previous iteration's reads
        As[ac2 * 4 + 0][ar] = av0.x;
        As[ac2 * 4 + 1][ar] = av0.y;
        As[ac2 * 4 + 2][ar] = av0.z;
        As[ac2 * 4 + 3][ar] = av0.w;
        As[ac2 * 4 + 4][ar] = av1.x;
        As[ac2 * 4 + 5][ar] = av1.y;
        As[ac2 * 4 + 6][ar] = av1.z;
        As[ac2 * 4 + 7][ar] = av1.w;
        *(float4*)&Bs[bkr][bc * 4] = bv0;
        *(float4*)&Bs[bkr][bc * 4 + 4] = bv1;
        __syncthreads();
#pragma unroll
        for (int kk = 0; kk < 16; kk++) {
            float4 a0 = *(const float4*)&As[kk][tm];
            float4 a1 = *(const float4*)&As[kk][tm + 4];
            float4 b0 = *(const float4*)&Bs[kk][tn];
            float4 b1 = *(const float4*)&Bs[kk][tn + 4];
            float av[8] = {a0.x, a0.y, a0.z, a0.w, a1.x, a1.y, a1.z, a1.w};
            float bv[8] = {b0.x, b0.y, b0.z, b0.w, b1.x, b1.y, b1.z, b1.w};
#pragma unroll
            for (int i = 0; i < 8; i++)
#pragma unroll
                for (int j = 0; j < 8; j++)
                    acc[i][j] = fmaf(av[i], bv[j], acc[i][j]);
        }
    }

    const bool isA = (bn < 4);
    float* Cout = isA ? Aout : Mout;
    const float* bias = isA ? tau_b : mem_b;
    const int ncol0 = (isA ? n0 : n0 - 512) + tn;
    float bj[8];
#pragma unroll
    for (int j = 0; j < 8; j++) bj[j] = bias[ncol0 + j];
#pragma unroll
    for (int i = 0; i < 8; i++) {
        size_t off = (size_t)(m0 + tm + i) * 512 + ncol0;
        float4 o0, o1;
        o0.x = acc[i][0] + bj[0]; o0.y = acc[i][1] + bj[1];
        o0.z = acc[i][2] + bj[2]; o0.w = acc[i][3] + bj[3];
        o1.x = acc[i][4] + bj[4]; o1.y = acc[i][5] + bj[5];
        o1.z = acc[i][6] + bj[6]; o1.w = acc[i][7] + bj[7];
        *(float4*)&Cout[off] = o0;
        *(float4*)&Cout[off + 4] = o1;
    }
}

// ---------------------------------------------------------------------------
// Kernel 3: reset sync state (runs every launch -> graph-replay safe).
// ---------------------------------------------------------------------------
__global__ void init_sync(float* __restrict__ xchg, int* __restrict__ flags) {
    int idx = blockIdx.x * 256 + threadIdx.x;
    if (idx < XCHG_HALF) xchg[idx] = 1.0f;
    if (idx < 256 * FSTRIDE) flags[idx] = 0;
}

// ---------------------------------------------------------------------------
// Kernel 4: cooperative scan. 256 blocks = (batch bb, channel-quarter cq).
// Each block owns 128 output channels; its 512x128 weight slice lives
// entirely in VGPRs (2 channels x 64 k per thread = 32 float4), kept
// resident via "+v" read-write asm pins INSIDE the loop (input-only pins
// let the compiler rematerialize the loads from global -> round-2 bug).
// ---------------------------------------------------------------------------
__global__ __launch_bounds__(512, 2)
void scan_sync(const float* __restrict__ WTh,
               const float* __restrict__ Mm,
               const float* __restrict__ log_thresh,
               float* __restrict__ AmOut,   // A in / spikes out (d_out)
               float* __restrict__ OutTail, // d_out base for tau/v tails
               float* __restrict__ xchg,
               int* __restrict__ flags) {
    __shared__ __align__(16) float tau_s[512];
    __shared__ __align__(16) float part[8][128];

    const int blk = blockIdx.x;
    const int bb = blk & 63;     // batch
    const int cq = blk >> 6;     // channel quarter 0..3
    const int tid = threadIdx.x;

    const int kg = tid >> 6;     // k-eighth 0..7 (wave-uniform)
    const int dd6 = tid & 63;
    const int k0 = kg << 6;

    const int gj = tid >> 7;     // tau segment this thread gathers/waits on
    const int gd = tid & 127;

    const int de = cq * 128 + (tid & 127);   // epilogue channel (tid<128)

    // weight fragment: channels c0 = cq*128+dd6, c1 = c0+64; k in [k0,k0+64)
    f32x4 w0[16], w1[16];
    {
        const int c0 = cq * 128 + dd6;
        const int c1 = c0 + 64;
#pragma unroll
        for (int j = 0; j < 16; j++) {
            int k = k0 + 4 * j;
            w0[j].x = WTh[(k + 0) * 512 + c0];
            w0[j].y = WTh[(k + 1) * 512 + c0];
            w0[j].z = WTh[(k + 2) * 512 + c0];
            w0[j].w = WTh[(k + 3) * 512 + c0];
            w1[j].x = WTh[(k + 0) * 512 + c1];
            w1[j].y = WTh[(k + 1) * 512 + c1];
            w1[j].z = WTh[(k + 2) * 512 + c1];
            w1[j].w = WTh[(k + 3) * 512 + c1];
        }
    }

    float thr = 0.f, v = 0.f, tau_new = 0.f;
    if (tid < 128) thr = 1.0f / (1.0f + expf(-log_thresh[de]));

    const f32x4* tau4 = (const f32x4*)tau_s;
    size_t abase = (size_t)bb * T_ * D_ + de;
    int* myflag = &flags[(bb * NGRP + cq) * FSTRIDE];
    const int* gflag = &flags[(bb * NGRP + gj) * FSTRIDE];
    const bool selfseg = (gj == cq);

    for (int c = 1; c <= T_; c++) {
        // Read-write pins: the asm "may modify" these VGPRs, so the compiler
        // CANNOT rematerialize them by reloading WTh — they stay live in
        // registers across the whole t-loop. Empty asm => zero instructions.
        asm volatile("" : "+v"(w0[0]), "+v"(w0[1]), "+v"(w0[2]), "+v"(w0[3]),
                          "+v"(w0[4]), "+v"(w0[5]), "+v"(w0[6]), "+v"(w0[7]));
        asm volatile("" : "+v"(w0[8]), "+v"(w0[9]), "+v"(w0[10]), "+v"(w0[11]),
                          "+v"(w0[12]), "+v"(w0[13]), "+v"(w0[14]), "+v"(w0[15]));
        asm volatile("" : "+v"(w1[0]), "+v"(w1[1]), "+v"(w1[2]), "+v"(w1[3]),
                          "+v"(w1[4]), "+v"(w1[5]), "+v"(w1[6]), "+v"(w1[7]));
        asm volatile("" : "+v"(w1[8]), "+v"(w1[9]), "+v"(w1[10]), "+v"(w1[11]),
                          "+v"(w1[12]), "+v"(w1[13]), "+v"(w1[14]), "+v"(w1[15]));

        // early-issue this step's A and M (consumed after GEMV)
        float a_in = 0.f, m_in = 0.f;
        if (tid < 128) { a_in = AmOut[abase]; m_in = Mm[abase]; }

        // wait for segment gj to have published s_{c-1}
        if (!selfseg) {
            while (__hip_atomic_load(gflag, __ATOMIC_RELAXED,
                                     __HIP_MEMORY_SCOPE_AGENT) < c - 1) {}
        }
        asm volatile("" ::: "memory");   // no load motion above the spin
        tau_s[tid] = __hip_atomic_load(
            &xchg[(size_t)((c - 1) & 1) * XCHG_HALF + gj * 8192 + bb * 128 + gd],
            __ATOMIC_RELAXED, __HIP_MEMORY_SCOPE_AGENT);
        __syncthreads();

        float acc0 = 0.f, acc1 = 0.f;
#pragma unroll
        for (int j = 0; j < 16; j++) {
            f32x4 tv = tau4[kg * 16 + j];     // wave-uniform LDS broadcast
            acc0 = fmaf(tv.x, w0[j].x, acc0);
            acc0 = fmaf(tv.y, w0[j].y, acc0);
            acc0 = fmaf(tv.z, w0[j].z, acc0);
            acc0 = fmaf(tv.w, w0[j].w, acc0);
            acc1 = fmaf(tv.x, w1[j].x, acc1);
            acc1 = fmaf(tv.y, w1[j].y, acc1);
            acc1 = fmaf(tv.z, w1[j].z, acc1);
            acc1 = fmaf(tv.w, w1[j].w, acc1);
        }
        part[kg][dd6] = acc0;
        part[kg][64 + dd6] = acc1;
        __syncthreads();

        if (tid < 128) {
            const int dch = tid;
            float p = ((part[0][dch] + part[1][dch]) + (part[2][dch] + part[3][dch]))
                    + ((part[4][dch] + part[5][dch]) + (part[6][dch] + part[7][dch]));
            float pre = p + a_in;
            tau_new = 1.0f / (1.0f + expf(-pre));
            float alpha = expf(-1.0f / (tau_new + 1e-6f));
            v = alpha * v + (1.0f - alpha) * m_in;
            float s = (v >= thr) ? 1.0f : 0.0f;
            AmOut[abase] = s;           // overwrite A slot with spike
            v = v * (1.0f - s);
            __hip_atomic_store(
                &xchg[(size_t)(c & 1) * XCHG_HALF + cq * 8192 + bb * 128 + tid],
                tau_new, __ATOMIC_RELAXED, __HIP_MEMORY_SCOPE_AGENT);
            abase += D_;
        }
        __syncthreads();   // publish stores drained before flag
        if (tid == 0)
            __hip_atomic_store(myflag, c, __ATOMIC_RELEASE,
                               __HIP_MEMORY_SCOPE_AGENT);
    }

    if (tid < 128) {
        OutTail[(size_t)BT_ * D_ + (size_t)bb * D_ + de] = tau_new;
        OutTail[(size_t)BT_ * D_ + (size_t)B_ * D_ + (size_t)bb * D_ + de] = v;
    }
}

// ---------------------------------------------------------------------------
extern "C" void kernel_launch(void* const* d_in, const int* in_sizes, int n_in,
                              void* d_out, int out_size, void* d_ws, size_t ws_size,
                              hipStream_t stream) {
    (void)in_sizes; (void)n_in; (void)out_size; (void)ws_size;
    const float* x          = (const float*)d_in[0];
    const float* tau_w      = (const float*)d_in[1];
    const float* tau_b      = (const float*)d_in[2];
    const float* mem_w      = (const float*)d_in[3];
    const float* mem_b      = (const float*)d_in[4];
    const float* log_thresh = (const float*)d_in[5];
    float* out = (float*)d_out;

    // workspace layout
    float* Wcat = (float*)d_ws;            // 512*1024 (dead after GEMM)
    float* WTh  = Wcat + 512 * 1024;       // 512*512
    float* Mout = WTh + 512 * 512;         // 131072*512
    // sync state reuses the Wcat region (GEMM is done before init_sync runs)
    float* xchg  = Wcat;                              // 2*XCHG_HALF floats
    int*   flags = (int*)(Wcat + 2 * XCHG_HALF);      // 256*FSTRIDE ints

    float* Aout = out;                     // spikes region doubles as A buffer

    prep_weights<<<2048, 256, 0, stream>>>(tau_w, mem_w, Wcat, WTh);
    gemm_xw<<<dim3(8, 1024), 256, 0, stream>>>(x, Wcat, tau_b, mem_b, Aout, Mout);
    init_sync<<<128, 256, 0, stream>>>(xchg, flags);

    const float* WThc = WTh;
    const float* Mmc  = Mout;
    const float* ltc  = log_thresh;
    float* outp = out;
    float* xchgp = xchg;
    int* flagsp = flags;
    void* args[7] = {(void*)&WThc, (void*)&Mmc, (void*)&ltc,
                     (void*)&Aout, (void*)&outp, (void*)&xchgp, (void*)&flagsp};
    hipLaunchCooperativeKernel((const void*)scan_sync, dim3(256), dim3(512),
                               args, 0, stream);
}

// Round 4
// 11432.355 us; speedup vs baseline: 1.0937x; 1.0260x over previous
//
#include <hip/hip_runtime.h>
#include <math.h>

#define B_ 64
#define T_ 2048
#define D_ 512
#define BT_ (B_ * T_)   // 131072
#define NGRP 4          // blocks per batch (channel quarters)
#define FSTRIDE 16      // flag padding (ints)
#define XCHG_HALF (NGRP * 64 * 128)   // 32768 floats per parity slot

typedef float f32x4 __attribute__((ext_vector_type(4)));

// ---------------------------------------------------------------------------
// Kernel 1: weight prep (transpose to k-major for coalesced GEMM/GEMV reads)
// ---------------------------------------------------------------------------
__global__ void prep_weights(const float* __restrict__ tau_w,
                             const float* __restrict__ mem_w,
                             float* __restrict__ Wcat,
                             float* __restrict__ WTh) {
    int idx = blockIdx.x * 256 + threadIdx.x;   // 0 .. 524287
    {
        int k = idx >> 10, j = idx & 1023;
        float v = (j < 512) ? tau_w[j * 1024 + k] : mem_w[(j - 512) * 512 + k];
        Wcat[idx] = v;
    }
    if (idx < 512 * 512) {
        int k = idx >> 9, d = idx & 511;
        WTh[idx] = tau_w[d * 1024 + 512 + k];
    }
}

// ---------------------------------------------------------------------------
// Kernel 2: f32 GEMM  C[131072][1024] = X[131072][512] @ Wcat[512][1024] + bias
// ---------------------------------------------------------------------------
__global__ __launch_bounds__(256, 2)
void gemm_xw(const float* __restrict__ X, const float* __restrict__ Wc,
             const float* __restrict__ tau_b, const float* __restrict__ mem_b,
             float* __restrict__ Aout, float* __restrict__ Mout) {
    __shared__ __align__(16) float As[16][128];  // [k][m]
    __shared__ __align__(16) float Bs[16][128];  // [k][n]
    const int bn = blockIdx.x;          // 0..7
    const int bm = blockIdx.y;          // 0..1023
    const int tid = threadIdx.x;
    const int tm = (tid >> 4) << 3;
    const int tn = (tid & 15) << 3;
    const int m0 = bm * 128, n0 = bn * 128;

    const float4* X4 = (const float4*)X;
    const float4* Wc4 = (const float4*)Wc;

    float acc[8][8];
#pragma unroll
    for (int i = 0; i < 8; i++)
#pragma unroll
        for (int j = 0; j < 8; j++) acc[i][j] = 0.0f;

    const int ar = tid >> 1;              // 0..127 row in tile
    const int ac2 = (tid & 1) * 2;        // float4 col 0 or 2
    const int bkr = tid >> 4;             // 0..15
    const int bc = (tid & 15) * 2;        // float4 col 0..30

    for (int kt = 0; kt < 512; kt += 16) {
        float4 av0 = X4[(m0 + ar) * 128 + (kt >> 2) + ac2];
        float4 av1 = X4[(m0 + ar) * 128 + (kt >> 2) + ac2 + 1];
        float4 bv0 = Wc4[(kt + bkr) * 256 + bn * 32 + bc];
        float4 bv1 = Wc4[(kt + bkr) * 256 + bn * 32 + bc + 1];
        __syncthreads();   // protect previous iteration's reads
        As[ac2 * 4 + 0][ar] = av0.x;
        As[ac2 * 4 + 1][ar] = av0.y;
        As[ac2 * 4 + 2][ar] = av0.z;
        As[ac2 * 4 + 3][ar] = av0.w;
        As[ac2 * 4 + 4][ar] = av1.x;
        As[ac2 * 4 + 5][ar] = av1.y;
        As[ac2 * 4 + 6][ar] = av1.z;
        As[ac2 * 4 + 7][ar] = av1.w;
        *(float4*)&Bs[bkr][bc * 4] = bv0;
        *(float4*)&Bs[bkr][bc * 4 + 4] = bv1;
        __syncthreads();
#pragma unroll
        for (int kk = 0; kk < 16; kk++) {
            float4 a0 = *(const float4*)&As[kk][tm];
            float4 a1 = *(const float4*)&As[kk][tm + 4];
            float4 b0 = *(const float4*)&Bs[kk][tn];
            float4 b1 = *(const float4*)&Bs[kk][tn + 4];
            float av[8] = {a0.x, a0.y, a0.z, a0.w, a1.x, a1.y, a1.z, a1.w};
            float bv[8] = {b0.x, b0.y, b0.z, b0.w, b1.x, b1.y, b1.z, b1.w};
#pragma unroll
            for (int i = 0; i < 8; i++)
#pragma unroll
                for (int j = 0; j < 8; j++)
                    acc[i][j] = fmaf(av[i], bv[j], acc[i][j]);
        }
    }

    const bool isA = (bn < 4);
    float* Cout = isA ? Aout : Mout;
    const float* bias = isA ? tau_b : mem_b;
    const int ncol0 = (isA ? n0 : n0 - 512) + tn;
    float bj[8];
#pragma unroll
    for (int j = 0; j < 8; j++) bj[j] = bias[ncol0 + j];
#pragma unroll
    for (int i = 0; i < 8; i++) {
        size_t off = (size_t)(m0 + tm + i) * 512 + ncol0;
        float4 o0, o1;
        o0.x = acc[i][0] + bj[0]; o0.y = acc[i][1] + bj[1];
        o0.z = acc[i][2] + bj[2]; o0.w = acc[i][3] + bj[3];
        o1.x = acc[i][4] + bj[4]; o1.y = acc[i][5] + bj[5];
        o1.z = acc[i][6] + bj[6]; o1.w = acc[i][7] + bj[7];
        *(float4*)&Cout[off] = o0;
        *(float4*)&Cout[off + 4] = o1;
    }
}

// ---------------------------------------------------------------------------
// Kernel 3: reset sync state (runs every launch -> graph-replay safe).
// ---------------------------------------------------------------------------
__global__ void init_sync(float* __restrict__ xchg, int* __restrict__ flags) {
    int idx = blockIdx.x * 256 + threadIdx.x;
    if (idx < XCHG_HALF) xchg[idx] = 1.0f;
    if (idx < 256 * FSTRIDE) flags[idx] = 0;
}

// ---------------------------------------------------------------------------
// Kernel 4: cooperative scan. 256 blocks = (batch bb, channel-quarter cq).
// Each block owns 128 output channels; its 512x128 weight slice lives
// entirely in VGPRs (2 channels x 64 k per thread = 32 float4).
// amdgpu_waves_per_eu(2,2): min=max=2 waves/EU tells the register allocator
// the TRUE occupancy (grid = 1 block/CU = 8 waves = 2/EU), giving it the
// full 256-VGPR budget. Round-3 lesson: __launch_bounds__(512,2) is only a
// FLOOR — the allocator still chased 6 waves/EU and spilled the weights.
// ---------------------------------------------------------------------------
__global__ __launch_bounds__(512)
__attribute__((amdgpu_waves_per_eu(2, 2)))
void scan_sync(const float* __restrict__ WTh,
               const float* __restrict__ Mm,
               const float* __restrict__ log_thresh,
               float* __restrict__ AmOut,   // A in / spikes out (d_out)
               float* __restrict__ OutTail, // d_out base for tau/v tails
               float* __restrict__ xchg,
               int* __restrict__ flags) {
    __shared__ __align__(16) float tau_s[512];
    __shared__ __align__(16) float part[8][128];

    const int blk = blockIdx.x;
    const int bb = blk & 63;     // batch
    const int cq = blk >> 6;     // channel quarter 0..3
    const int tid = threadIdx.x;

    const int kg = tid >> 6;     // k-eighth 0..7 (wave-uniform)
    const int dd6 = tid & 63;
    const int k0 = kg << 6;

    const int gj = tid >> 7;     // tau segment this thread gathers/waits on
    const int gd = tid & 127;

    const int de = cq * 128 + (tid & 127);   // epilogue channel (tid<128)

    // weight fragment: channels c0 = cq*128+dd6, c1 = c0+64; k in [k0,k0+64)
    f32x4 w0[16], w1[16];
    {
        const int c0 = cq * 128 + dd6;
        const int c1 = c0 + 64;
#pragma unroll
        for (int j = 0; j < 16; j++) {
            int k = k0 + 4 * j;
            w0[j].x = WTh[(k + 0) * 512 + c0];
            w0[j].y = WTh[(k + 1) * 512 + c0];
            w0[j].z = WTh[(k + 2) * 512 + c0];
            w0[j].w = WTh[(k + 3) * 512 + c0];
            w1[j].x = WTh[(k + 0) * 512 + c1];
            w1[j].y = WTh[(k + 1) * 512 + c1];
            w1[j].z = WTh[(k + 2) * 512 + c1];
            w1[j].w = WTh[(k + 3) * 512 + c1];
        }
    }

    float thr = 0.f, v = 0.f, tau_new = 0.f;
    if (tid < 128) thr = 1.0f / (1.0f + expf(-log_thresh[de]));

    const f32x4* tau4 = (const f32x4*)tau_s;
    size_t abase = (size_t)bb * T_ * D_ + de;
    int* myflag = &flags[(bb * NGRP + cq) * FSTRIDE];
    const int* gflag = &flags[(bb * NGRP + gj) * FSTRIDE];
    const bool selfseg = (gj == cq);

    for (int c = 1; c <= T_; c++) {
        // Read-write pins: keep the weight fragment live in VGPRs across the
        // loop back-edge (remat of the WTh loads is illegal past these).
        asm volatile("" : "+v"(w0[0]), "+v"(w0[1]), "+v"(w0[2]), "+v"(w0[3]),
                          "+v"(w0[4]), "+v"(w0[5]), "+v"(w0[6]), "+v"(w0[7]));
        asm volatile("" : "+v"(w0[8]), "+v"(w0[9]), "+v"(w0[10]), "+v"(w0[11]),
                          "+v"(w0[12]), "+v"(w0[13]), "+v"(w0[14]), "+v"(w0[15]));
        asm volatile("" : "+v"(w1[0]), "+v"(w1[1]), "+v"(w1[2]), "+v"(w1[3]),
                          "+v"(w1[4]), "+v"(w1[5]), "+v"(w1[6]), "+v"(w1[7]));
        asm volatile("" : "+v"(w1[8]), "+v"(w1[9]), "+v"(w1[10]), "+v"(w1[11]),
                          "+v"(w1[12]), "+v"(w1[13]), "+v"(w1[14]), "+v"(w1[15]));

        // early-issue this step's A and M (consumed after GEMV)
        float a_in = 0.f, m_in = 0.f;
        if (tid < 128) { a_in = AmOut[abase]; m_in = Mm[abase]; }

        // wait for segment gj to have published s_{c-1}
        if (!selfseg) {
            while (__hip_atomic_load(gflag, __ATOMIC_RELAXED,
                                     __HIP_MEMORY_SCOPE_AGENT) < c - 1) {}
        }
        asm volatile("" ::: "memory");   // no load motion above the spin
        tau_s[tid] = __hip_atomic_load(
            &xchg[(size_t)((c - 1) & 1) * XCHG_HALF + gj * 8192 + bb * 128 + gd],
            __ATOMIC_RELAXED, __HIP_MEMORY_SCOPE_AGENT);
        __syncthreads();

        float acc0 = 0.f, acc1 = 0.f;
#pragma unroll
        for (int j = 0; j < 16; j++) {
            f32x4 tv = tau4[kg * 16 + j];     // wave-uniform LDS broadcast
            acc0 = fmaf(tv.x, w0[j].x, acc0);
            acc0 = fmaf(tv.y, w0[j].y, acc0);
            acc0 = fmaf(tv.z, w0[j].z, acc0);
            acc0 = fmaf(tv.w, w0[j].w, acc0);
            acc1 = fmaf(tv.x, w1[j].x, acc1);
            acc1 = fmaf(tv.y, w1[j].y, acc1);
            acc1 = fmaf(tv.z, w1[j].z, acc1);
            acc1 = fmaf(tv.w, w1[j].w, acc1);
        }
        part[kg][dd6] = acc0;
        part[kg][64 + dd6] = acc1;
        __syncthreads();

        if (tid < 128) {
            const int dch = tid;
            float p = ((part[0][dch] + part[1][dch]) + (part[2][dch] + part[3][dch]))
                    + ((part[4][dch] + part[5][dch]) + (part[6][dch] + part[7][dch]));
            float pre = p + a_in;
            tau_new = 1.0f / (1.0f + expf(-pre));
            float alpha = expf(-1.0f / (tau_new + 1e-6f));
            v = alpha * v + (1.0f - alpha) * m_in;
            float s = (v >= thr) ? 1.0f : 0.0f;
            AmOut[abase] = s;           // overwrite A slot with spike
            v = v * (1.0f - s);
            __hip_atomic_store(
                &xchg[(size_t)(c & 1) * XCHG_HALF + cq * 8192 + bb * 128 + tid],
                tau_new, __ATOMIC_RELAXED, __HIP_MEMORY_SCOPE_AGENT);
            abase += D_;
        }
        __syncthreads();   // publish stores drained before flag
        if (tid == 0)
            __hip_atomic_store(myflag, c, __ATOMIC_RELEASE,
                               __HIP_MEMORY_SCOPE_AGENT);
    }

    if (tid < 128) {
        OutTail[(size_t)BT_ * D_ + (size_t)bb * D_ + de] = tau_new;
        OutTail[(size_t)BT_ * D_ + (size_t)B_ * D_ + (size_t)bb * D_ + de] = v;
    }
}

// ---------------------------------------------------------------------------
extern "C" void kernel_launch(void* const* d_in, const int* in_sizes, int n_in,
                              void* d_out, int out_size, void* d_ws, size_t ws_size,
                              hipStream_t stream) {
    (void)in_sizes; (void)n_in; (void)out_size; (void)ws_size;
    const float* x          = (const float*)d_in[0];
    const float* tau_w      = (const float*)d_in[1];
    const float* tau_b      = (const float*)d_in[2];
    const float* mem_w      = (const float*)d_in[3];
    const float* mem_b      = (const float*)d_in[4];
    const float* log_thresh = (const float*)d_in[5];
    float* out = (float*)d_out;

    // workspace layout
    float* Wcat = (float*)d_ws;            // 512*1024 (dead after GEMM)
    float* WTh  = Wcat + 512 * 1024;       // 512*512
    float* Mout = WTh + 512 * 512;         // 131072*512
    // sync state reuses the Wcat region (GEMM is done before init_sync runs)
    float* xchg  = Wcat;                              // 2*XCHG_HALF floats
    int*   flags = (int*)(Wcat + 2 * XCHG_HALF);      // 256*FSTRIDE ints

    float* Aout = out;                     // spikes region doubles as A buffer

    prep_weights<<<2048, 256, 0, stream>>>(tau_w, mem_w, Wcat, WTh);
    gemm_xw<<<dim3(8, 1024), 256, 0, stream>>>(x, Wcat, tau_b, mem_b, Aout, Mout);
    init_sync<<<128, 256, 0, stream>>>(xchg, flags);

    const float* WThc = WTh;
    const float* Mmc  = Mout;
    const float* ltc  = log_thresh;
    float* outp = out;
    float* xchgp = xchg;
    int* flagsp = flags;
    void* args[7] = {(void*)&WThc, (void*)&Mmc, (void*)&ltc,
                     (void*)&Aout, (void*)&outp, (void*)&xchgp, (void*)&flagsp};
    hipLaunchCooperativeKernel((const void*)scan_sync, dim3(256), dim3(512),
                               args, 0, stream);
}